// Round 6
// baseline (175.948 us; speedup 1.0000x reference)
//
#include <hip/hip_runtime.h>
#include <math.h>

// Model dims: B=1024, S=16, E=32, NH=4, H=64 (lstm1), 32 (lstm2)
// lstm_kernel: 64 blocks x 256 threads, 16 batch elems/block, MFMA bf16 gates.
// One barrier per step; fast rcp-based activations; cvt_pk_bf16 packing.

typedef __attribute__((ext_vector_type(8))) short short8v;   // 8 bf16 = 4 VGPR
typedef __attribute__((ext_vector_type(4))) float f32x4;

__device__ __forceinline__ float sigf(float x) {
    float e = __expf(-x);
    return __builtin_amdgcn_rcpf(1.0f + e);
}
__device__ __forceinline__ float tanh_f(float x) {
    float a = fabsf(x);
    float e = __expf(2.0f * a);
    float t = 1.0f - 2.0f * __builtin_amdgcn_rcpf(e + 1.0f);
    return copysignf(t, x);
}
__device__ __forceinline__ unsigned short f2bf(float f) {   // RTN f32->bf16 (preamble only)
    unsigned int u = __float_as_uint(f);
    unsigned int r = (u + 0x7FFFu + ((u >> 16) & 1u)) >> 16;
    return (unsigned short)r;
}
__device__ __forceinline__ unsigned cvtpk_bf16(float lo, float hi) {  // D.lo=bf16(lo), D.hi=bf16(hi)
    unsigned r;
    asm("v_cvt_pk_bf16_f32 %0, %1, %2" : "=v"(r) : "v"(lo), "v"(hi));
    return r;
}

// ---------------- fused embed+posenc+LSTM1+LSTM2+residual+QKV via MFMA ----------------
__global__ __launch_bounds__(256, 1) void lstm_kernel(
    const float* __restrict__ x,
    const float* __restrict__ emb_w, const float* __restrict__ emb_b,
    const float* __restrict__ wih1, const float* __restrict__ whh1,
    const float* __restrict__ bih1, const float* __restrict__ bhh1,
    const float* __restrict__ wih2, const float* __restrict__ whh2,
    const float* __restrict__ bih2, const float* __restrict__ bhh2,
    const float* __restrict__ attn_w, const float* __restrict__ attn_b,
    float* __restrict__ Q, float* __restrict__ K, float* __restrict__ V) {
    const int tid = threadIdx.x;
    const int w = tid >> 6, lane = tid & 63;
    const int l15 = lane & 15, q4 = lane >> 4;
    const int base = blockIdx.x * 16;

    __shared__ __align__(16) unsigned char E_raw[16 * 1024];   // E[16s][16j][32 bf16] swz
    __shared__ __align__(16) unsigned char H1_raw[2][2048];    // h1[buf][16j][64 bf16] swz
    __shared__ __align__(16) unsigned char H2_raw[2][1024];    // h2[buf][16j][32 bf16] swz
    __shared__ __align__(16) unsigned char WF2[24 * 1024];     // LSTM2 A-frags, fragment-linear
    __shared__ __align__(16) float L1F[16][64];
    __shared__ __align__(16) float L2F[16][32];

    const unsigned jx7 = (unsigned)(l15 & 7) << 4;   // H1 row = 128B: XOR bits 4-6
    const unsigned jx4 = (unsigned)(l15 & 3) << 4;   // H2/E row = 64B: XOR bits 4-5

    // ---- LSTM1 weight A-fragments in registers ----
    short8v w1f[4][3];   // tiles T = w + 4t (t = gate kind), slabs over [W1hh(64)|W1ih(32)]
#pragma unroll
    for (int t = 0; t < 4; t++) {
        const int row = (w + 4 * t) * 16 + l15;
#pragma unroll
        for (int sl = 0; sl < 3; sl++) {
            short8v f;
#pragma unroll
            for (int e = 0; e < 8; e++) {
                int k = sl * 32 + q4 * 8 + e;
                float v = (k < 64) ? whh1[row * 64 + k] : wih1[row * 32 + (k - 64)];
                f[e] = (short)f2bf(v);
            }
            w1f[t][sl] = f;
        }
    }

    // ---- stage LSTM2 A-fragments to LDS ----
    for (int f = w; f < 24; f += 4) {
        int t2 = f / 3, sl = f - t2 * 3;
        int row = t2 * 16 + l15;
        int koff = sl * 32 + q4 * 8;
        const float* src = (sl < 2) ? (wih2 + row * 64 + koff) : (whh2 + row * 32 + (koff - 64));
        float4 va = *(const float4*)(src);
        float4 vb = *(const float4*)(src + 4);
        short8v pk;
        pk[0] = (short)f2bf(va.x); pk[1] = (short)f2bf(va.y);
        pk[2] = (short)f2bf(va.z); pk[3] = (short)f2bf(va.w);
        pk[4] = (short)f2bf(vb.x); pk[5] = (short)f2bf(vb.y);
        pk[6] = (short)f2bf(vb.z); pk[7] = (short)f2bf(vb.w);
        *(short8v*)(&WF2[f * 1024 + lane * 16]) = pk;
    }

    // ---- biases ----
    float b1r[4][4];
#pragma unroll
    for (int t = 0; t < 4; t++)
#pragma unroll
        for (int e = 0; e < 4; e++) {
            int r = (w + 4 * t) * 16 + q4 * 4 + e;
            b1r[t][e] = bih1[r] + bhh1[r];
        }
    float b2r[4][4];
#pragma unroll
    for (int t = 0; t < 4; t++)
#pragma unroll
        for (int e = 0; e < 4; e++) {
            int r = ((w & 1) + 2 * t) * 16 + q4 * 4 + e;
            b2r[t][e] = bih2[r] + bhh2[r];
        }

    // ---- init: zero h buffers [1] (read by step 0), build E ----
    *(unsigned long long*)(H1_raw[1] + tid * 8) = 0ULL;
    if (tid < 128) *(unsigned long long*)(H2_raw[1] + tid * 8) = 0ULL;
    {
        const int je = tid >> 4, se = tid & 15;
        float xv = x[(base + je) * 16 + se];
        float ev[32];
#pragma unroll
        for (int ii = 0; ii < 16; ii++) {
            float d = __expf(-0.28782313662425574f * (float)(2 * ii));  // 10000^(-2i/32)
            float ang = (float)se * d;
            ev[2 * ii] = xv * emb_w[2 * ii] + emb_b[2 * ii] + __sinf(ang);
            ev[2 * ii + 1] = xv * emb_w[2 * ii + 1] + emb_b[2 * ii + 1] + __cosf(ang);
        }
        unsigned jm = (unsigned)(je & 3) << 4;
#pragma unroll
        for (int b = 0; b < 4; b++) {
            short8v pk;
#pragma unroll
            for (int e = 0; e < 8; e++) pk[e] = (short)f2bf(ev[b * 8 + e]);
            *(short8v*)(&E_raw[se * 1024 + je * 64 + (((unsigned)(b * 16)) ^ jm)]) = pk;
        }
    }
    float c1[4] = {0.f, 0.f, 0.f, 0.f};
    float c2[4] = {0.f, 0.f, 0.f, 0.f};

    const int u0 = w * 16 + q4 * 4;

#define LDBE(S)  (*(const short8v*)(&E_raw[(S) * 1024] + (((unsigned)(l15 * 64 + q4 * 16)) ^ jx4)))
#define LDB0(HP) (*(const short8v*)((HP) + (((unsigned)(l15 * 128 + q4 * 16)) ^ jx7)))
#define LDB1(HP) (*(const short8v*)((HP) + (((unsigned)(l15 * 128 + 64 + q4 * 16)) ^ jx7)))
#define LDC2(HP) (*(const short8v*)((HP) + (((unsigned)(l15 * 64 + q4 * 16)) ^ jx4)))
#define L2FRAG(T, SL) (*(const short8v*)(&WF2[(((w + 2 * (T)) * 3 + (SL)) << 10) + lane * 16]))

    // phase1: gates1 + act1 + h1 write. BE-slab MFMA first (regs), hides B0/B1 latency.
    auto phase1 = [&](unsigned char* H1n, short8v BE, short8v B0, short8v B1, bool last) {
        f32x4 a0 = {b1r[0][0], b1r[0][1], b1r[0][2], b1r[0][3]};
        f32x4 a1 = {b1r[1][0], b1r[1][1], b1r[1][2], b1r[1][3]};
        f32x4 a2 = {b1r[2][0], b1r[2][1], b1r[2][2], b1r[2][3]};
        f32x4 a3 = {b1r[3][0], b1r[3][1], b1r[3][2], b1r[3][3]};
        a0 = __builtin_amdgcn_mfma_f32_16x16x32_bf16(w1f[0][2], BE, a0, 0, 0, 0);
        a1 = __builtin_amdgcn_mfma_f32_16x16x32_bf16(w1f[1][2], BE, a1, 0, 0, 0);
        a2 = __builtin_amdgcn_mfma_f32_16x16x32_bf16(w1f[2][2], BE, a2, 0, 0, 0);
        a3 = __builtin_amdgcn_mfma_f32_16x16x32_bf16(w1f[3][2], BE, a3, 0, 0, 0);
        a0 = __builtin_amdgcn_mfma_f32_16x16x32_bf16(w1f[0][0], B0, a0, 0, 0, 0);
        a1 = __builtin_amdgcn_mfma_f32_16x16x32_bf16(w1f[1][0], B0, a1, 0, 0, 0);
        a2 = __builtin_amdgcn_mfma_f32_16x16x32_bf16(w1f[2][0], B0, a2, 0, 0, 0);
        a3 = __builtin_amdgcn_mfma_f32_16x16x32_bf16(w1f[3][0], B0, a3, 0, 0, 0);
        a0 = __builtin_amdgcn_mfma_f32_16x16x32_bf16(w1f[0][1], B1, a0, 0, 0, 0);
        a1 = __builtin_amdgcn_mfma_f32_16x16x32_bf16(w1f[1][1], B1, a1, 0, 0, 0);
        a2 = __builtin_amdgcn_mfma_f32_16x16x32_bf16(w1f[2][1], B1, a2, 0, 0, 0);
        a3 = __builtin_amdgcn_mfma_f32_16x16x32_bf16(w1f[3][1], B1, a3, 0, 0, 0);
        float h1v[4];
#pragma unroll
        for (int e = 0; e < 4; e++) {
            c1[e] = sigf(a1[e]) * c1[e] + sigf(a0[e]) * tanh_f(a2[e]);
            h1v[e] = sigf(a3[e]) * tanh_f(c1[e]);
        }
        uint2 pk = make_uint2(cvtpk_bf16(h1v[0], h1v[1]), cvtpk_bf16(h1v[2], h1v[3]));
        *(uint2*)(H1n + (((unsigned)(l15 * 128 + u0 * 2)) ^ jx7)) = pk;
        if (last) *(float4*)(&L1F[l15][u0]) = make_float4(h1v[0], h1v[1], h1v[2], h1v[3]);
    };

    __syncthreads();
    // phase1(0): reads zeros from H1_raw[1], writes H1_raw[0]
    phase1(H1_raw[0], LDBE(0), LDB0(H1_raw[1]), LDB1(H1_raw[1]), false);

#pragma unroll 2
    for (int s = 0; s < 16; s++) {
        const int p = s & 1;
        __syncthreads();   // h1(s) visible (and h2(s-1) cross-wave frags)
        short8v BEn = LDBE((s < 15) ? (s + 1) : 15);
        short8v B0 = LDB0(H1_raw[p]);
        short8v B1 = LDB1(H1_raw[p]);
        if (w < 2) {
            // ---- phase2(s): LSTM2 gates over [h1(s); h2(s-1)], weights from LDS ----
            short8v C2 = LDC2(H2_raw[p ^ 1]);
            f32x4 d0 = {b2r[0][0], b2r[0][1], b2r[0][2], b2r[0][3]};
            f32x4 d1 = {b2r[1][0], b2r[1][1], b2r[1][2], b2r[1][3]};
            f32x4 d2 = {b2r[2][0], b2r[2][1], b2r[2][2], b2r[2][3]};
            f32x4 d3 = {b2r[3][0], b2r[3][1], b2r[3][2], b2r[3][3]};
            d0 = __builtin_amdgcn_mfma_f32_16x16x32_bf16(L2FRAG(0, 0), B0, d0, 0, 0, 0);
            d1 = __builtin_amdgcn_mfma_f32_16x16x32_bf16(L2FRAG(1, 0), B0, d1, 0, 0, 0);
            d2 = __builtin_amdgcn_mfma_f32_16x16x32_bf16(L2FRAG(2, 0), B0, d2, 0, 0, 0);
            d3 = __builtin_amdgcn_mfma_f32_16x16x32_bf16(L2FRAG(3, 0), B0, d3, 0, 0, 0);
            d0 = __builtin_amdgcn_mfma_f32_16x16x32_bf16(L2FRAG(0, 1), B1, d0, 0, 0, 0);
            d1 = __builtin_amdgcn_mfma_f32_16x16x32_bf16(L2FRAG(1, 1), B1, d1, 0, 0, 0);
            d2 = __builtin_amdgcn_mfma_f32_16x16x32_bf16(L2FRAG(2, 1), B1, d2, 0, 0, 0);
            d3 = __builtin_amdgcn_mfma_f32_16x16x32_bf16(L2FRAG(3, 1), B1, d3, 0, 0, 0);
            d0 = __builtin_amdgcn_mfma_f32_16x16x32_bf16(L2FRAG(0, 2), C2, d0, 0, 0, 0);
            d1 = __builtin_amdgcn_mfma_f32_16x16x32_bf16(L2FRAG(1, 2), C2, d1, 0, 0, 0);
            d2 = __builtin_amdgcn_mfma_f32_16x16x32_bf16(L2FRAG(2, 2), C2, d2, 0, 0, 0);
            d3 = __builtin_amdgcn_mfma_f32_16x16x32_bf16(L2FRAG(3, 2), C2, d3, 0, 0, 0);
            float h2v[4];
#pragma unroll
            for (int e = 0; e < 4; e++) {
                c2[e] = sigf(d1[e]) * c2[e] + sigf(d0[e]) * tanh_f(d2[e]);
                h2v[e] = sigf(d3[e]) * tanh_f(c2[e]);
            }
            uint2 pk = make_uint2(cvtpk_bf16(h2v[0], h2v[1]), cvtpk_bf16(h2v[2], h2v[3]));
            *(uint2*)(H2_raw[p] + (((unsigned)(l15 * 64 + u0 * 2)) ^ jx4)) = pk;
            if (s == 15) *(float4*)(&L2F[l15][u0]) = make_float4(h2v[0], h2v[1], h2v[2], h2v[3]);
        }
        if (s < 15) phase1(H1_raw[p ^ 1], BEn, B0, B1, (s + 1) == 15);
    }

    __syncthreads();
    // ---- epilogue: residual + QKV projection ----
    {
        const int j = tid >> 4, rb = tid & 15;
        const int gb = base + j;
        const float4* l1p = (const float4*)(&L1F[j][0]);
        const float4* l2p = (const float4*)(&L2F[j][0]);
#pragma unroll
        for (int rep = 0; rep < 6; rep++) {
            int row = rb + 16 * rep;   // 0..95
            float acc = attn_b[row];
            const float4* wrow = (const float4*)(attn_w + row * 32);
#pragma unroll
            for (int k4 = 0; k4 < 8; k4++) {
                float4 lv1 = l1p[k4];
                float4 lv2 = l2p[k4];
                float4 ww = wrow[k4];
                float lx = lv2.x + lv1.x, ly = lv2.y + lv1.y, lz = lv2.z + lv1.z, lw = lv2.w + lv1.w;
                acc += lx * ww.x + ly * ww.y + lz * ww.z + lw * ww.w;
            }
            if (row < 32) Q[gb * 32 + row] = acc * 0.35355339059327373f;  // 1/sqrt(8)
            else if (row < 64) K[gb * 32 + (row - 32)] = acc;
            else V[gb * 32 + (row - 64)] = acc;
        }
    }
#undef LDBE
#undef LDB0
#undef LDB1
#undef LDC2
#undef L2FRAG
}

// ---------------- fused attention (over batch dim) + MLP head. One wave per query l.
// lane = (h, ks): head h = lane>>4, key-slice ks = lane&15; each lane streams 64 keys.
__global__ __launch_bounds__(256) void attn_head_kernel(
    const float* __restrict__ Q, const float* __restrict__ K, const float* __restrict__ V,
    const float* __restrict__ ow, const float* __restrict__ ob,
    const float* __restrict__ d1w, const float* __restrict__ d1b,
    const float* __restrict__ g1, const float* __restrict__ bn1b,
    const float* __restrict__ d2w, const float* __restrict__ d2b,
    const float* __restrict__ g2, const float* __restrict__ bn2b,
    const float* __restrict__ d3w, const float* __restrict__ d3b,
    float* __restrict__ out) {
    int wid = threadIdx.x >> 6, lane = threadIdx.x & 63;
    int l = blockIdx.x * 4 + wid;
    int h = lane >> 4, ks = lane & 15;
    __shared__ float att_s[4][32], z_s[4][32], r1s[4][64];

    const float4* qp = (const float4*)(Q + l * 32 + h * 8);
    float4 q0 = qp[0], q1 = qp[1];
    float m = -1e30f, den = 0.f;
    float4 acc0 = {0, 0, 0, 0}, acc1 = {0, 0, 0, 0};
#pragma unroll 4
    for (int t = 0; t < 64; t++) {
        int key = t * 16 + ks;
        const float4* kp = (const float4*)(K + key * 32 + h * 8);
        float4 ka = kp[0], kb = kp[1];
        const float4* vp = (const float4*)(V + key * 32 + h * 8);
        float4 va = vp[0], vb = vp[1];
        float s = q0.x * ka.x + q0.y * ka.y + q0.z * ka.z + q0.w * ka.w +
                  q1.x * kb.x + q1.y * kb.y + q1.z * kb.z + q1.w * kb.w;
        float nm = fmaxf(m, s);
        float f = __expf(m - nm), pp = __expf(s - nm);
        den = den * f + pp;
        acc0.x = acc0.x * f + pp * va.x;
        acc0.y = acc0.y * f + pp * va.y;
        acc0.z = acc0.z * f + pp * va.z;
        acc0.w = acc0.w * f + pp * va.w;
        acc1.x = acc1.x * f + pp * vb.x;
        acc1.y = acc1.y * f + pp * vb.y;
        acc1.z = acc1.z * f + pp * vb.z;
        acc1.w = acc1.w * f + pp * vb.w;
        m = nm;
    }
    // combine 16 key-slices (butterfly within each 16-lane head group)
#pragma unroll
    for (int d = 1; d < 16; d <<= 1) {
        float m2 = __shfl_xor(m, d), den2 = __shfl_xor(den, d);
        float4 b0, b1;
        b0.x = __shfl_xor(acc0.x, d); b0.y = __shfl_xor(acc0.y, d);
        b0.z = __shfl_xor(acc0.z, d); b0.w = __shfl_xor(acc0.w, d);
        b1.x = __shfl_xor(acc1.x, d); b1.y = __shfl_xor(acc1.y, d);
        b1.z = __shfl_xor(acc1.z, d); b1.w = __shfl_xor(acc1.w, d);
        float nm = fmaxf(m, m2);
        float f = __expf(m - nm), f2 = __expf(m2 - nm);
        den = den * f + den2 * f2;
        acc0.x = acc0.x * f + b0.x * f2;
        acc0.y = acc0.y * f + b0.y * f2;
        acc0.z = acc0.z * f + b0.z * f2;
        acc0.w = acc0.w * f + b0.w * f2;
        acc1.x = acc1.x * f + b1.x * f2;
        acc1.y = acc1.y * f + b1.y * f2;
        acc1.z = acc1.z * f + b1.z * f2;
        acc1.w = acc1.w * f + b1.w * f2;
        m = nm;
    }
    float r = __builtin_amdgcn_rcpf(den);
    if (ks == 0) {
        float4 o0 = make_float4(acc0.x * r, acc0.y * r, acc0.z * r, acc0.w * r);
        float4 o1 = make_float4(acc1.x * r, acc1.y * r, acc1.z * r, acc1.w * r);
        *(float4*)(&att_s[wid][h * 8]) = o0;
        *(float4*)(&att_s[wid][h * 8 + 4]) = o1;
    }
    __syncthreads();
    int j = lane;
    if (j < 32) {
        float a = ob[j];
        const float4* aw = (const float4*)(&att_s[wid][0]);
        const float4* wr = (const float4*)(ow + j * 32);
#pragma unroll
        for (int k4 = 0; k4 < 8; k4++) {
            float4 u = aw[k4], wv = wr[k4];
            a += u.x * wv.x + u.y * wv.y + u.z * wv.z + u.w * wv.w;
        }
        z_s[wid][j] = a;
    }
    __syncthreads();
    const float inv = rsqrtf(1.0f + 1e-5f);
    {
        float a = d1b[j];
        const float4* zw = (const float4*)(&z_s[wid][0]);
        const float4* wr = (const float4*)(d1w + j * 32);
#pragma unroll
        for (int k4 = 0; k4 < 8; k4++) {
            float4 u = zw[k4], wv = wr[k4];
            a += u.x * wv.x + u.y * wv.y + u.z * wv.z + u.w * wv.w;
        }
        a = a * (g1[j] * inv) + bn1b[j];
        r1s[wid][j] = fmaxf(a, 0.f);
    }
    __syncthreads();
    if (j < 32) {
        float a = d2b[j];
        const float4* rw = (const float4*)(&r1s[wid][0]);
        const float4* wr = (const float4*)(d2w + j * 64);
#pragma unroll
        for (int k4 = 0; k4 < 16; k4++) {
            float4 u = rw[k4], wv = wr[k4];
            a += u.x * wv.x + u.y * wv.y + u.z * wv.z + u.w * wv.w;
        }
        a = a * (g2[j] * inv) + bn2b[j];
        float r2 = fmaxf(a, 0.f);
        float p = r2 * d3w[j];
        p += __shfl_down(p, 16);
        p += __shfl_down(p, 8);
        p += __shfl_down(p, 4);
        p += __shfl_down(p, 2);
        p += __shfl_down(p, 1);
        if (j == 0) out[l] = __builtin_amdgcn_rcpf(1.0f + __expf(-(p + d3b[0])));
    }
}

extern "C" void kernel_launch(void* const* d_in, const int* in_sizes, int n_in,
                              void* d_out, int out_size, void* d_ws, size_t ws_size,
                              hipStream_t stream) {
    const float* x      = (const float*)d_in[0];
    const float* emb_w  = (const float*)d_in[1];
    const float* emb_b  = (const float*)d_in[2];
    const float* l1_wih = (const float*)d_in[3];
    const float* l1_whh = (const float*)d_in[4];
    const float* l1_bih = (const float*)d_in[5];
    const float* l1_bhh = (const float*)d_in[6];
    const float* l2_wih = (const float*)d_in[7];
    const float* l2_whh = (const float*)d_in[8];
    const float* l2_bih = (const float*)d_in[9];
    const float* l2_bhh = (const float*)d_in[10];
    const float* attn_w = (const float*)d_in[11];
    const float* attn_b = (const float*)d_in[12];
    const float* attn_ow = (const float*)d_in[13];
    const float* attn_ob = (const float*)d_in[14];
    const float* d1_w  = (const float*)d_in[15];
    const float* d1_b  = (const float*)d_in[16];
    const float* bn1_g = (const float*)d_in[17];
    const float* bn1_b = (const float*)d_in[18];
    const float* d2_w  = (const float*)d_in[19];
    const float* d2_b  = (const float*)d_in[20];
    const float* bn2_g = (const float*)d_in[21];
    const float* bn2_b = (const float*)d_in[22];
    const float* d3_w  = (const float*)d_in[23];
    const float* d3_b  = (const float*)d_in[24];
    float* out = (float*)d_out;

    float* ws = (float*)d_ws;
    float* Q  = ws;               // 32768
    float* K  = ws + 32768;       // 32768
    float* V  = ws + 65536;       // 32768

    lstm_kernel<<<64, 256, 0, stream>>>(x, emb_w, emb_b, l1_wih, l1_whh, l1_bih, l1_bhh,
                                        l2_wih, l2_whh, l2_bih, l2_bhh,
                                        attn_w, attn_b, Q, K, V);
    attn_head_kernel<<<256, 256, 0, stream>>>(Q, K, V, attn_ow, attn_ob, d1_w, d1_b,
                                              bn1_g, bn1_b, d2_w, d2_b, bn2_g, bn2_b,
                                              d3_w, d3_b, out);
}

// Round 8
// 144.188 us; speedup vs baseline: 1.2203x; 1.2203x over previous
//
#include <hip/hip_runtime.h>
#include <math.h>

// Model dims: B=1024, S=16, E=32, NH=4, H=64 (lstm1), 32 (lstm2)
// lstm_kernel: 64 blocks x 256 threads, 16 batch elems/block, MFMA bf16 gates.
// One barrier per step; fast rcp-based activations; cvt_pk_bf16 packing.

typedef __attribute__((ext_vector_type(8))) short short8v;   // 8 bf16 = 4 VGPR
typedef __attribute__((ext_vector_type(4))) float f32x4;

__device__ __forceinline__ float sigf(float x) {
    float e = __expf(-x);
    return __builtin_amdgcn_rcpf(1.0f + e);
}
__device__ __forceinline__ float tanh_f(float x) {
    float a = fabsf(x);
    float e = __expf(2.0f * a);
    float t = 1.0f - 2.0f * __builtin_amdgcn_rcpf(e + 1.0f);
    return copysignf(t, x);
}
__device__ __forceinline__ unsigned short f2bf(float f) {   // RTN f32->bf16 (preamble only)
    unsigned int u = __float_as_uint(f);
    unsigned int r = (u + 0x7FFFu + ((u >> 16) & 1u)) >> 16;
    return (unsigned short)r;
}
__device__ __forceinline__ unsigned cvtpk_bf16(float lo, float hi) {  // D.lo=bf16(lo), D.hi=bf16(hi)
    unsigned r;
    asm("v_cvt_pk_bf16_f32 %0, %1, %2" : "=v"(r) : "v"(lo), "v"(hi));
    return r;
}

// ---------------- fused embed+posenc+LSTM1+LSTM2+residual+QKV via MFMA ----------------
__global__ __launch_bounds__(256, 1) void lstm_kernel(
    const float* __restrict__ x,
    const float* __restrict__ emb_w, const float* __restrict__ emb_b,
    const float* __restrict__ wih1, const float* __restrict__ whh1,
    const float* __restrict__ bih1, const float* __restrict__ bhh1,
    const float* __restrict__ wih2, const float* __restrict__ whh2,
    const float* __restrict__ bih2, const float* __restrict__ bhh2,
    const float* __restrict__ attn_w, const float* __restrict__ attn_b,
    float* __restrict__ Q, float* __restrict__ K, float* __restrict__ V) {
    const int tid = threadIdx.x;
    const int w = tid >> 6, lane = tid & 63;
    const int l15 = lane & 15, q4 = lane >> 4;
    const int base = blockIdx.x * 16;

    __shared__ __align__(16) unsigned char E_raw[16 * 1024];   // E[16s][16j][32 bf16] swz
    __shared__ __align__(16) unsigned char H1_raw[2][2048];    // h1[buf][16j][64 bf16] swz
    __shared__ __align__(16) unsigned char H2_raw[2][1024];    // h2[buf][16j][32 bf16] swz
    __shared__ __align__(16) unsigned char WF2[24 * 1024];     // LSTM2 A-frags, fragment-linear
    __shared__ __align__(16) float L1F[16][64];
    __shared__ __align__(16) float L2F[16][32];

    const unsigned jx7 = (unsigned)(l15 & 7) << 4;   // H1 row = 128B: XOR bits 4-6
    const unsigned jx4 = (unsigned)(l15 & 3) << 4;   // H2/E row = 64B: XOR bits 4-5

    // ---- LSTM1 weight A-fragments in registers ----
    short8v w1f[4][3];   // tiles T = w + 4t (t = gate kind), slabs over [W1hh(64)|W1ih(32)]
#pragma unroll
    for (int t = 0; t < 4; t++) {
        const int row = (w + 4 * t) * 16 + l15;
#pragma unroll
        for (int sl = 0; sl < 3; sl++) {
            short8v f;
#pragma unroll
            for (int e = 0; e < 8; e++) {
                int k = sl * 32 + q4 * 8 + e;
                float v = (k < 64) ? whh1[row * 64 + k] : wih1[row * 32 + (k - 64)];
                f[e] = (short)f2bf(v);
            }
            w1f[t][sl] = f;
        }
    }

    // ---- stage LSTM2 A-fragments to LDS ----
    for (int f = w; f < 24; f += 4) {
        int t2 = f / 3, sl = f - t2 * 3;
        int row = t2 * 16 + l15;
        int koff = sl * 32 + q4 * 8;
        const float* src = (sl < 2) ? (wih2 + row * 64 + koff) : (whh2 + row * 32 + (koff - 64));
        float4 va = *(const float4*)(src);
        float4 vb = *(const float4*)(src + 4);
        short8v pk;
        pk[0] = (short)f2bf(va.x); pk[1] = (short)f2bf(va.y);
        pk[2] = (short)f2bf(va.z); pk[3] = (short)f2bf(va.w);
        pk[4] = (short)f2bf(vb.x); pk[5] = (short)f2bf(vb.y);
        pk[6] = (short)f2bf(vb.z); pk[7] = (short)f2bf(vb.w);
        *(short8v*)(&WF2[f * 1024 + lane * 16]) = pk;
    }

    // ---- biases ----
    float b1r[4][4];
#pragma unroll
    for (int t = 0; t < 4; t++)
#pragma unroll
        for (int e = 0; e < 4; e++) {
            int r = (w + 4 * t) * 16 + q4 * 4 + e;
            b1r[t][e] = bih1[r] + bhh1[r];
        }
    float b2r[4][4];
#pragma unroll
    for (int t = 0; t < 4; t++)
#pragma unroll
        for (int e = 0; e < 4; e++) {
            int r = ((w & 1) + 2 * t) * 16 + q4 * 4 + e;
            b2r[t][e] = bih2[r] + bhh2[r];
        }

    // ---- init: zero h buffers [1] (read by step 0), build E ----
    *(unsigned long long*)(H1_raw[1] + tid * 8) = 0ULL;
    if (tid < 128) *(unsigned long long*)(H2_raw[1] + tid * 8) = 0ULL;
    {
        const int je = tid >> 4, se = tid & 15;
        float xv = x[(base + je) * 16 + se];
        float ev[32];
#pragma unroll
        for (int ii = 0; ii < 16; ii++) {
            float d = __expf(-0.28782313662425574f * (float)(2 * ii));  // 10000^(-2i/32)
            float ang = (float)se * d;
            ev[2 * ii] = xv * emb_w[2 * ii] + emb_b[2 * ii] + __sinf(ang);
            ev[2 * ii + 1] = xv * emb_w[2 * ii + 1] + emb_b[2 * ii + 1] + __cosf(ang);
        }
        unsigned jm = (unsigned)(je & 3) << 4;
#pragma unroll
        for (int b = 0; b < 4; b++) {
            short8v pk;
#pragma unroll
            for (int e = 0; e < 8; e++) pk[e] = (short)f2bf(ev[b * 8 + e]);
            *(short8v*)(&E_raw[se * 1024 + je * 64 + (((unsigned)(b * 16)) ^ jm)]) = pk;
        }
    }
    float c1[4] = {0.f, 0.f, 0.f, 0.f};
    float c2[4] = {0.f, 0.f, 0.f, 0.f};

    const int u0 = w * 16 + q4 * 4;

#define LDBE(S)  (*(const short8v*)(&E_raw[(S) * 1024] + (((unsigned)(l15 * 64 + q4 * 16)) ^ jx4)))
#define LDB0(HP) (*(const short8v*)((HP) + (((unsigned)(l15 * 128 + q4 * 16)) ^ jx7)))
#define LDB1(HP) (*(const short8v*)((HP) + (((unsigned)(l15 * 128 + 64 + q4 * 16)) ^ jx7)))
#define LDC2(HP) (*(const short8v*)((HP) + (((unsigned)(l15 * 64 + q4 * 16)) ^ jx4)))
#define L2FRAG(T, SL) (*(const short8v*)(&WF2[(((w + 2 * (T)) * 3 + (SL)) << 10) + lane * 16]))

    // phase1: gates1 + act1 + h1 write. BE-slab MFMA first (regs), hides B0/B1 latency.
    auto phase1 = [&](unsigned char* H1n, short8v BE, short8v B0, short8v B1, bool last) {
        f32x4 a0 = {b1r[0][0], b1r[0][1], b1r[0][2], b1r[0][3]};
        f32x4 a1 = {b1r[1][0], b1r[1][1], b1r[1][2], b1r[1][3]};
        f32x4 a2 = {b1r[2][0], b1r[2][1], b1r[2][2], b1r[2][3]};
        f32x4 a3 = {b1r[3][0], b1r[3][1], b1r[3][2], b1r[3][3]};
        a0 = __builtin_amdgcn_mfma_f32_16x16x32_bf16(w1f[0][2], BE, a0, 0, 0, 0);
        a1 = __builtin_amdgcn_mfma_f32_16x16x32_bf16(w1f[1][2], BE, a1, 0, 0, 0);
        a2 = __builtin_amdgcn_mfma_f32_16x16x32_bf16(w1f[2][2], BE, a2, 0, 0, 0);
        a3 = __builtin_amdgcn_mfma_f32_16x16x32_bf16(w1f[3][2], BE, a3, 0, 0, 0);
        a0 = __builtin_amdgcn_mfma_f32_16x16x32_bf16(w1f[0][0], B0, a0, 0, 0, 0);
        a1 = __builtin_amdgcn_mfma_f32_16x16x32_bf16(w1f[1][0], B0, a1, 0, 0, 0);
        a2 = __builtin_amdgcn_mfma_f32_16x16x32_bf16(w1f[2][0], B0, a2, 0, 0, 0);
        a3 = __builtin_amdgcn_mfma_f32_16x16x32_bf16(w1f[3][0], B0, a3, 0, 0, 0);
        a0 = __builtin_amdgcn_mfma_f32_16x16x32_bf16(w1f[0][1], B1, a0, 0, 0, 0);
        a1 = __builtin_amdgcn_mfma_f32_16x16x32_bf16(w1f[1][1], B1, a1, 0, 0, 0);
        a2 = __builtin_amdgcn_mfma_f32_16x16x32_bf16(w1f[2][1], B1, a2, 0, 0, 0);
        a3 = __builtin_amdgcn_mfma_f32_16x16x32_bf16(w1f[3][1], B1, a3, 0, 0, 0);
        float h1v[4];
#pragma unroll
        for (int e = 0; e < 4; e++) {
            c1[e] = sigf(a1[e]) * c1[e] + sigf(a0[e]) * tanh_f(a2[e]);
            h1v[e] = sigf(a3[e]) * tanh_f(c1[e]);
        }
        uint2 pk = make_uint2(cvtpk_bf16(h1v[0], h1v[1]), cvtpk_bf16(h1v[2], h1v[3]));
        *(uint2*)(H1n + (((unsigned)(l15 * 128 + u0 * 2)) ^ jx7)) = pk;
        if (last) *(float4*)(&L1F[l15][u0]) = make_float4(h1v[0], h1v[1], h1v[2], h1v[3]);
    };

    __syncthreads();
    // phase1(0): reads zeros from H1_raw[1], writes H1_raw[0]
    phase1(H1_raw[0], LDBE(0), LDB0(H1_raw[1]), LDB1(H1_raw[1]), false);

#pragma unroll 2
    for (int s = 0; s < 16; s++) {
        const int p = s & 1;
        __syncthreads();   // h1(s) visible (and h2(s-1) cross-wave frags)
        short8v BEn = LDBE((s < 15) ? (s + 1) : 15);
        short8v B0 = LDB0(H1_raw[p]);
        short8v B1 = LDB1(H1_raw[p]);
        if (w < 2) {
            // ---- phase2(s): LSTM2 gates over [h1(s); h2(s-1)], weights from LDS ----
            short8v C2 = LDC2(H2_raw[p ^ 1]);
            f32x4 d0 = {b2r[0][0], b2r[0][1], b2r[0][2], b2r[0][3]};
            f32x4 d1 = {b2r[1][0], b2r[1][1], b2r[1][2], b2r[1][3]};
            f32x4 d2 = {b2r[2][0], b2r[2][1], b2r[2][2], b2r[2][3]};
            f32x4 d3 = {b2r[3][0], b2r[3][1], b2r[3][2], b2r[3][3]};
            d0 = __builtin_amdgcn_mfma_f32_16x16x32_bf16(L2FRAG(0, 0), B0, d0, 0, 0, 0);
            d1 = __builtin_amdgcn_mfma_f32_16x16x32_bf16(L2FRAG(1, 0), B0, d1, 0, 0, 0);
            d2 = __builtin_amdgcn_mfma_f32_16x16x32_bf16(L2FRAG(2, 0), B0, d2, 0, 0, 0);
            d3 = __builtin_amdgcn_mfma_f32_16x16x32_bf16(L2FRAG(3, 0), B0, d3, 0, 0, 0);
            d0 = __builtin_amdgcn_mfma_f32_16x16x32_bf16(L2FRAG(0, 1), B1, d0, 0, 0, 0);
            d1 = __builtin_amdgcn_mfma_f32_16x16x32_bf16(L2FRAG(1, 1), B1, d1, 0, 0, 0);
            d2 = __builtin_amdgcn_mfma_f32_16x16x32_bf16(L2FRAG(2, 1), B1, d2, 0, 0, 0);
            d3 = __builtin_amdgcn_mfma_f32_16x16x32_bf16(L2FRAG(3, 1), B1, d3, 0, 0, 0);
            d0 = __builtin_amdgcn_mfma_f32_16x16x32_bf16(L2FRAG(0, 2), C2, d0, 0, 0, 0);
            d1 = __builtin_amdgcn_mfma_f32_16x16x32_bf16(L2FRAG(1, 2), C2, d1, 0, 0, 0);
            d2 = __builtin_amdgcn_mfma_f32_16x16x32_bf16(L2FRAG(2, 2), C2, d2, 0, 0, 0);
            d3 = __builtin_amdgcn_mfma_f32_16x16x32_bf16(L2FRAG(3, 2), C2, d3, 0, 0, 0);
            float h2v[4];
#pragma unroll
            for (int e = 0; e < 4; e++) {
                c2[e] = sigf(d1[e]) * c2[e] + sigf(d0[e]) * tanh_f(d2[e]);
                h2v[e] = sigf(d3[e]) * tanh_f(c2[e]);
            }
            uint2 pk = make_uint2(cvtpk_bf16(h2v[0], h2v[1]), cvtpk_bf16(h2v[2], h2v[3]));
            *(uint2*)(H2_raw[p] + (((unsigned)(l15 * 64 + u0 * 2)) ^ jx4)) = pk;
            if (s == 15) *(float4*)(&L2F[l15][u0]) = make_float4(h2v[0], h2v[1], h2v[2], h2v[3]);
        }
        if (s < 15) phase1(H1_raw[p ^ 1], BEn, B0, B1, (s + 1) == 15);
    }

    __syncthreads();
    // ---- epilogue: residual + QKV projection ----
    {
        const int j = tid >> 4, rb = tid & 15;
        const int gb = base + j;
        const float4* l1p = (const float4*)(&L1F[j][0]);
        const float4* l2p = (const float4*)(&L2F[j][0]);
#pragma unroll
        for (int rep = 0; rep < 6; rep++) {
            int row = rb + 16 * rep;   // 0..95
            float acc = attn_b[row];
            const float4* wrow = (const float4*)(attn_w + row * 32);
#pragma unroll
            for (int k4 = 0; k4 < 8; k4++) {
                float4 lv1 = l1p[k4];
                float4 lv2 = l2p[k4];
                float4 ww = wrow[k4];
                float lx = lv2.x + lv1.x, ly = lv2.y + lv1.y, lz = lv2.z + lv1.z, lw = lv2.w + lv1.w;
                acc += lx * ww.x + ly * ww.y + lz * ww.z + lw * ww.w;
            }
            if (row < 32) Q[gb * 32 + row] = acc * 0.35355339059327373f;  // 1/sqrt(8)
            else if (row < 64) K[gb * 32 + (row - 32)] = acc;
            else V[gb * 32 + (row - 64)] = acc;
        }
    }
#undef LDBE
#undef LDB0
#undef LDB1
#undef LDC2
#undef L2FRAG
}

// ---------------- attention over batch dim. 16 chunks x 16 l-tiles = 256 blocks.
// block: (c, lt); threads: h = t>>6 (wave-uniform), l = lt*64 + (t&63)
__global__ __launch_bounds__(256, 2) void attn_kernel(
    const float* __restrict__ Q, const float* __restrict__ K, const float* __restrict__ V,
    float* __restrict__ pm, float* __restrict__ ps, float* __restrict__ pacc) {
    int c = blockIdx.x & 15, lt = blockIdx.x >> 4;
    int t = threadIdx.x;
    int h = t >> 6, l = lt * 64 + (t & 63);
    __shared__ __align__(16) float Ks[64 * 32];
    __shared__ __align__(16) float Vs[64 * 32];
    {
        const float4* Kg = (const float4*)(K + c * 2048);
        const float4* Vg = (const float4*)(V + c * 2048);
        float4* K4 = (float4*)Ks;
        float4* V4 = (float4*)Vs;
        K4[t] = Kg[t];
        K4[t + 256] = Kg[t + 256];
        V4[t] = Vg[t];
        V4[t + 256] = Vg[t + 256];
    }
    const float4* qg = (const float4*)(Q + l * 32 + h * 8);
    float4 q0 = qg[0], q1 = qg[1];
    __syncthreads();
    float m_r = -1e30f, l_r = 0.f;
    float4 acc0 = {0, 0, 0, 0}, acc1 = {0, 0, 0, 0};
#pragma unroll 4
    for (int m = 0; m < 64; m++) {
        const float4* k4 = (const float4*)(Ks + m * 32 + h * 8);
        float4 ka = k4[0], kb = k4[1];
        float s = q0.x * ka.x + q0.y * ka.y + q0.z * ka.z + q0.w * ka.w +
                  q1.x * kb.x + q1.y * kb.y + q1.z * kb.z + q1.w * kb.w;
        const float4* v4 = (const float4*)(Vs + m * 32 + h * 8);
        float4 va = v4[0], vb = v4[1];
        float nm = fmaxf(m_r, s);
        float f = __expf(m_r - nm);
        float pp = __expf(s - nm);
        l_r = l_r * f + pp;
        acc0.x = acc0.x * f + pp * va.x;
        acc0.y = acc0.y * f + pp * va.y;
        acc0.z = acc0.z * f + pp * va.z;
        acc0.w = acc0.w * f + pp * va.w;
        acc1.x = acc1.x * f + pp * vb.x;
        acc1.y = acc1.y * f + pp * vb.y;
        acc1.z = acc1.z * f + pp * vb.z;
        acc1.w = acc1.w * f + pp * vb.w;
        m_r = nm;
    }
    int idx = (c * 4 + h) * 1024 + l;
    pm[idx] = m_r;
    ps[idx] = l_r;
    float4* po = (float4*)(pacc + idx * 8);
    po[0] = acc0;
    po[1] = acc1;
}

// ---------------- combine 16 chunks + out-proj + MLP head + sigmoid. One wave per l.
__global__ __launch_bounds__(256) void head_kernel(
    const float* __restrict__ pm, const float* __restrict__ ps, const float* __restrict__ pacc,
    const float* __restrict__ ow, const float* __restrict__ ob,
    const float* __restrict__ d1w, const float* __restrict__ d1b,
    const float* __restrict__ g1, const float* __restrict__ b1,
    const float* __restrict__ d2w, const float* __restrict__ d2b,
    const float* __restrict__ g2, const float* __restrict__ b2,
    const float* __restrict__ d3w, const float* __restrict__ d3b,
    float* __restrict__ out) {
    int wid = threadIdx.x >> 6, j = threadIdx.x & 63;
    int l = blockIdx.x * 4 + wid;
    __shared__ float att_s[4][32], z_s[4][32], r1s[4][64];
    if (j < 32) {
        int h = j >> 3, d = j & 7;
        float M = -1e30f;
#pragma unroll
        for (int c = 0; c < 16; c++) M = fmaxf(M, pm[(c * 4 + h) * 1024 + l]);
        float den = 0.f, num = 0.f;
#pragma unroll
        for (int c = 0; c < 16; c++) {
            int idx = (c * 4 + h) * 1024 + l;
            float e = __expf(pm[idx] - M);
            den += e * ps[idx];
            num += e * pacc[idx * 8 + d];
        }
        att_s[wid][j] = num / den;
    }
    __syncthreads();
    if (j < 32) {
        float a = ob[j];
        const float4* aw = (const float4*)(&att_s[wid][0]);
        const float4* wr = (const float4*)(ow + j * 32);
#pragma unroll
        for (int k4 = 0; k4 < 8; k4++) {
            float4 u = aw[k4], wv = wr[k4];
            a += u.x * wv.x + u.y * wv.y + u.z * wv.z + u.w * wv.w;
        }
        z_s[wid][j] = a;
    }
    __syncthreads();
    const float inv = rsqrtf(1.0f + 1e-5f);
    {
        float a = d1b[j];
        const float4* zw = (const float4*)(&z_s[wid][0]);
        const float4* wr = (const float4*)(d1w + j * 32);
#pragma unroll
        for (int k4 = 0; k4 < 8; k4++) {
            float4 u = zw[k4], wv = wr[k4];
            a += u.x * wv.x + u.y * wv.y + u.z * wv.z + u.w * wv.w;
        }
        a = a * (g1[j] * inv) + b1[j];
        r1s[wid][j] = fmaxf(a, 0.f);
    }
    __syncthreads();
    if (j < 32) {
        float a = d2b[j];
        const float4* rw = (const float4*)(&r1s[wid][0]);
        const float4* wr = (const float4*)(d2w + j * 64);
#pragma unroll
        for (int k4 = 0; k4 < 16; k4++) {
            float4 u = rw[k4], wv = wr[k4];
            a += u.x * wv.x + u.y * wv.y + u.z * wv.z + u.w * wv.w;
        }
        a = a * (g2[j] * inv) + b2[j];
        float r2 = fmaxf(a, 0.f);
        float p = r2 * d3w[j];
        p += __shfl_down(p, 16);
        p += __shfl_down(p, 8);
        p += __shfl_down(p, 4);
        p += __shfl_down(p, 2);
        p += __shfl_down(p, 1);
        if (j == 0) out[l] = __builtin_amdgcn_rcpf(1.0f + __expf(-(p + d3b[0])));
    }
}

extern "C" void kernel_launch(void* const* d_in, const int* in_sizes, int n_in,
                              void* d_out, int out_size, void* d_ws, size_t ws_size,
                              hipStream_t stream) {
    const float* x      = (const float*)d_in[0];
    const float* emb_w  = (const float*)d_in[1];
    const float* emb_b  = (const float*)d_in[2];
    const float* l1_wih = (const float*)d_in[3];
    const float* l1_whh = (const float*)d_in[4];
    const float* l1_bih = (const float*)d_in[5];
    const float* l1_bhh = (const float*)d_in[6];
    const float* l2_wih = (const float*)d_in[7];
    const float* l2_whh = (const float*)d_in[8];
    const float* l2_bih = (const float*)d_in[9];
    const float* l2_bhh = (const float*)d_in[10];
    const float* attn_w = (const float*)d_in[11];
    const float* attn_b = (const float*)d_in[12];
    const float* attn_ow = (const float*)d_in[13];
    const float* attn_ob = (const float*)d_in[14];
    const float* d1_w  = (const float*)d_in[15];
    const float* d1_b  = (const float*)d_in[16];
    const float* bn1_g = (const float*)d_in[17];
    const float* bn1_b = (const float*)d_in[18];
    const float* d2_w  = (const float*)d_in[19];
    const float* d2_b  = (const float*)d_in[20];
    const float* bn2_g = (const float*)d_in[21];
    const float* bn2_b = (const float*)d_in[22];
    const float* d3_w  = (const float*)d_in[23];
    const float* d3_b  = (const float*)d_in[24];
    float* out = (float*)d_out;

    float* ws   = (float*)d_ws;
    float* Q    = ws;               // 32768
    float* K    = ws + 32768;       // 32768
    float* V    = ws + 65536;       // 32768
    float* pm   = ws + 98304;       // 65536
    float* ps   = ws + 163840;      // 65536
    float* pacc = ws + 229376;      // 524288   (end: 753664 floats ~2.95 MB)

    lstm_kernel<<<64, 256, 0, stream>>>(x, emb_w, emb_b, l1_wih, l1_whh, l1_bih, l1_bhh,
                                        l2_wih, l2_whh, l2_bih, l2_bhh,
                                        attn_w, attn_b, Q, K, V);
    attn_kernel<<<256, 256, 0, stream>>>(Q, K, V, pm, ps, pacc);
    head_kernel<<<256, 256, 0, stream>>>(pm, ps, pacc, attn_ow, attn_ob, d1_w, d1_b,
                                         bn1_g, bn1_b, d2_w, d2_b, bn2_g, bn2_b,
                                         d3_w, d3_b, out);
}

// Round 10
// 142.358 us; speedup vs baseline: 1.2360x; 1.0129x over previous
//
#include <hip/hip_runtime.h>
#include <math.h>

// Model dims: B=1024, S=16, E=32, NH=4, H=64 (lstm1), 32 (lstm2)
// lstm_kernel: 64 blocks x 256 threads, 16 batch elems/block, MFMA bf16 gates.
// R9: LSTM2 weight frags hoisted to registers (loaded once from LDS);
//     per-step LDS reads batched into one cluster after the barrier.

typedef __attribute__((ext_vector_type(8))) short short8v;   // 8 bf16 = 4 VGPR
typedef __attribute__((ext_vector_type(4))) float f32x4;

__device__ __forceinline__ float sigf(float x) {
    float e = __expf(-x);
    return __builtin_amdgcn_rcpf(1.0f + e);
}
__device__ __forceinline__ float tanh_f(float x) {
    float a = fabsf(x);
    float e = __expf(2.0f * a);
    float t = 1.0f - 2.0f * __builtin_amdgcn_rcpf(e + 1.0f);
    return copysignf(t, x);
}
__device__ __forceinline__ unsigned short f2bf(float f) {   // RTN f32->bf16 (preamble only)
    unsigned int u = __float_as_uint(f);
    unsigned int r = (u + 0x7FFFu + ((u >> 16) & 1u)) >> 16;
    return (unsigned short)r;
}
__device__ __forceinline__ unsigned cvtpk_bf16(float lo, float hi) {  // D.lo=bf16(lo), D.hi=bf16(hi)
    unsigned r;
    asm("v_cvt_pk_bf16_f32 %0, %1, %2" : "=v"(r) : "v"(lo), "v"(hi));
    return r;
}

// ---------------- fused embed+posenc+LSTM1+LSTM2+residual+QKV via MFMA ----------------
__global__ __launch_bounds__(256, 1) void lstm_kernel(
    const float* __restrict__ x,
    const float* __restrict__ emb_w, const float* __restrict__ emb_b,
    const float* __restrict__ wih1, const float* __restrict__ whh1,
    const float* __restrict__ bih1, const float* __restrict__ bhh1,
    const float* __restrict__ wih2, const float* __restrict__ whh2,
    const float* __restrict__ bih2, const float* __restrict__ bhh2,
    const float* __restrict__ attn_w, const float* __restrict__ attn_b,
    float* __restrict__ Q, float* __restrict__ K, float* __restrict__ V) {
    const int tid = threadIdx.x;
    const int w = tid >> 6, lane = tid & 63;
    const int l15 = lane & 15, q4 = lane >> 4;
    const int base = blockIdx.x * 16;

    __shared__ __align__(16) unsigned char E_raw[16 * 1024];   // E[16s][16j][32 bf16] swz
    __shared__ __align__(16) unsigned char H1_raw[2][2048];    // h1[buf][16j][64 bf16] swz
    __shared__ __align__(16) unsigned char H2_raw[2][1024];    // h2[buf][16j][32 bf16] swz
    __shared__ __align__(16) unsigned char WF2[24 * 1024];     // LSTM2 A-frags (staging only)
    __shared__ __align__(16) float L1F[16][64];
    __shared__ __align__(16) float L2F[16][32];

    const unsigned jx7 = (unsigned)(l15 & 7) << 4;   // H1 row = 128B: XOR bits 4-6
    const unsigned jx4 = (unsigned)(l15 & 3) << 4;   // H2/E row = 64B: XOR bits 4-5

    // ---- LSTM1 weight A-fragments in registers ----
    short8v w1f[4][3];   // tiles T = w + 4t (t = gate kind), slabs over [W1hh(64)|W1ih(32)]
#pragma unroll
    for (int t = 0; t < 4; t++) {
        const int row = (w + 4 * t) * 16 + l15;
#pragma unroll
        for (int sl = 0; sl < 3; sl++) {
            short8v f;
#pragma unroll
            for (int e = 0; e < 8; e++) {
                int k = sl * 32 + q4 * 8 + e;
                float v = (k < 64) ? whh1[row * 64 + k] : wih1[row * 32 + (k - 64)];
                f[e] = (short)f2bf(v);
            }
            w1f[t][sl] = f;
        }
    }

    // ---- stage LSTM2 A-fragments to LDS (then hoisted to regs after the barrier) ----
    for (int f = w; f < 24; f += 4) {
        int t2 = f / 3, sl = f - t2 * 3;
        int row = t2 * 16 + l15;
        int koff = sl * 32 + q4 * 8;
        const float* src = (sl < 2) ? (wih2 + row * 64 + koff) : (whh2 + row * 32 + (koff - 64));
        float4 va = *(const float4*)(src);
        float4 vb = *(const float4*)(src + 4);
        short8v pk;
        pk[0] = (short)f2bf(va.x); pk[1] = (short)f2bf(va.y);
        pk[2] = (short)f2bf(va.z); pk[3] = (short)f2bf(va.w);
        pk[4] = (short)f2bf(vb.x); pk[5] = (short)f2bf(vb.y);
        pk[6] = (short)f2bf(vb.z); pk[7] = (short)f2bf(vb.w);
        *(short8v*)(&WF2[f * 1024 + lane * 16]) = pk;
    }

    // ---- biases ----
    float b1r[4][4];
#pragma unroll
    for (int t = 0; t < 4; t++)
#pragma unroll
        for (int e = 0; e < 4; e++) {
            int r = (w + 4 * t) * 16 + q4 * 4 + e;
            b1r[t][e] = bih1[r] + bhh1[r];
        }
    float b2r[4][4];
#pragma unroll
    for (int t = 0; t < 4; t++)
#pragma unroll
        for (int e = 0; e < 4; e++) {
            int r = ((w & 1) + 2 * t) * 16 + q4 * 4 + e;   // waves 2,3 mirror 0,1 (in-range)
            b2r[t][e] = bih2[r] + bhh2[r];
        }

    // ---- init: zero h buffers [1] (read by step 0), build E ----
    *(unsigned long long*)(H1_raw[1] + tid * 8) = 0ULL;
    if (tid < 128) *(unsigned long long*)(H2_raw[1] + tid * 8) = 0ULL;
    {
        const int je = tid >> 4, se = tid & 15;
        float xv = x[(base + je) * 16 + se];
        float ev[32];
#pragma unroll
        for (int ii = 0; ii < 16; ii++) {
            float d = __expf(-0.28782313662425574f * (float)(2 * ii));  // 10000^(-2i/32)
            float ang = (float)se * d;
            ev[2 * ii] = xv * emb_w[2 * ii] + emb_b[2 * ii] + __sinf(ang);
            ev[2 * ii + 1] = xv * emb_w[2 * ii + 1] + emb_b[2 * ii + 1] + __cosf(ang);
        }
        unsigned jm = (unsigned)(je & 3) << 4;
#pragma unroll
        for (int b = 0; b < 4; b++) {
            short8v pk;
#pragma unroll
            for (int e = 0; e < 8; e++) pk[e] = (short)f2bf(ev[b * 8 + e]);
            *(short8v*)(&E_raw[se * 1024 + je * 64 + (((unsigned)(b * 16)) ^ jm)]) = pk;
        }
    }
    float c1[4] = {0.f, 0.f, 0.f, 0.f};
    float c2[4] = {0.f, 0.f, 0.f, 0.f};

    const int u0 = w * 16 + q4 * 4;

#define LDBE(S)  (*(const short8v*)(&E_raw[(S) * 1024] + (((unsigned)(l15 * 64 + q4 * 16)) ^ jx4)))
#define LDB0(HP) (*(const short8v*)((HP) + (((unsigned)(l15 * 128 + q4 * 16)) ^ jx7)))
#define LDB1(HP) (*(const short8v*)((HP) + (((unsigned)(l15 * 128 + 64 + q4 * 16)) ^ jx7)))
#define LDC2(HP) (*(const short8v*)((HP) + (((unsigned)(l15 * 64 + q4 * 16)) ^ jx4)))

    __syncthreads();   // init + WF2 staging visible

    // ---- hoist LSTM2 weight frags to registers, ONCE, unconditionally (not sinkable) ----
    short8v w2r[12];   // [t*3+sl], tiles T2 = (w&1) + 2t
#pragma unroll
    for (int t = 0; t < 4; t++)
#pragma unroll
        for (int sl = 0; sl < 3; sl++)
            w2r[t * 3 + sl] =
                *(const short8v*)(&WF2[((((w & 1) + 2 * t) * 3 + sl) << 10) + lane * 16]);

    // phase1: gates1 + act1 + h1 write. BE-slab MFMA first (regs), hides B0/B1 latency.
    auto phase1 = [&](unsigned char* H1n, short8v BE, short8v B0, short8v B1, bool last) {
        f32x4 a0 = {b1r[0][0], b1r[0][1], b1r[0][2], b1r[0][3]};
        f32x4 a1 = {b1r[1][0], b1r[1][1], b1r[1][2], b1r[1][3]};
        f32x4 a2 = {b1r[2][0], b1r[2][1], b1r[2][2], b1r[2][3]};
        f32x4 a3 = {b1r[3][0], b1r[3][1], b1r[3][2], b1r[3][3]};
        a0 = __builtin_amdgcn_mfma_f32_16x16x32_bf16(w1f[0][2], BE, a0, 0, 0, 0);
        a1 = __builtin_amdgcn_mfma_f32_16x16x32_bf16(w1f[1][2], BE, a1, 0, 0, 0);
        a2 = __builtin_amdgcn_mfma_f32_16x16x32_bf16(w1f[2][2], BE, a2, 0, 0, 0);
        a3 = __builtin_amdgcn_mfma_f32_16x16x32_bf16(w1f[3][2], BE, a3, 0, 0, 0);
        a0 = __builtin_amdgcn_mfma_f32_16x16x32_bf16(w1f[0][0], B0, a0, 0, 0, 0);
        a1 = __builtin_amdgcn_mfma_f32_16x16x32_bf16(w1f[1][0], B0, a1, 0, 0, 0);
        a2 = __builtin_amdgcn_mfma_f32_16x16x32_bf16(w1f[2][0], B0, a2, 0, 0, 0);
        a3 = __builtin_amdgcn_mfma_f32_16x16x32_bf16(w1f[3][0], B0, a3, 0, 0, 0);
        a0 = __builtin_amdgcn_mfma_f32_16x16x32_bf16(w1f[0][1], B1, a0, 0, 0, 0);
        a1 = __builtin_amdgcn_mfma_f32_16x16x32_bf16(w1f[1][1], B1, a1, 0, 0, 0);
        a2 = __builtin_amdgcn_mfma_f32_16x16x32_bf16(w1f[2][1], B1, a2, 0, 0, 0);
        a3 = __builtin_amdgcn_mfma_f32_16x16x32_bf16(w1f[3][1], B1, a3, 0, 0, 0);
        float h1v[4];
#pragma unroll
        for (int e = 0; e < 4; e++) {
            c1[e] = sigf(a1[e]) * c1[e] + sigf(a0[e]) * tanh_f(a2[e]);
            h1v[e] = sigf(a3[e]) * tanh_f(c1[e]);
        }
        uint2 pk = make_uint2(cvtpk_bf16(h1v[0], h1v[1]), cvtpk_bf16(h1v[2], h1v[3]));
        *(uint2*)(H1n + (((unsigned)(l15 * 128 + u0 * 2)) ^ jx7)) = pk;
        if (last) *(float4*)(&L1F[l15][u0]) = make_float4(h1v[0], h1v[1], h1v[2], h1v[3]);
    };

    // phase1(0): reads zeros from H1_raw[1], writes H1_raw[0]
    phase1(H1_raw[0], LDBE(0), LDB0(H1_raw[1]), LDB1(H1_raw[1]), false);

#pragma unroll 2
    for (int s = 0; s < 16; s++) {
        const int p = s & 1;
        __syncthreads();   // h1(s) visible (and h2(s-1) cross-wave frags)
        // ---- batch ALL of this step's LDS reads into one issue cluster ----
        short8v B0 = LDB0(H1_raw[p]);
        short8v B1 = LDB1(H1_raw[p]);
        short8v BEn = LDBE((s < 15) ? (s + 1) : 15);
        short8v C2 = LDC2(H2_raw[p ^ 1]);
        if (w < 2) {
            // ---- phase2(s): LSTM2 gates over [h1(s); h2(s-1)], weights in regs ----
            f32x4 d0 = {b2r[0][0], b2r[0][1], b2r[0][2], b2r[0][3]};
            f32x4 d1 = {b2r[1][0], b2r[1][1], b2r[1][2], b2r[1][3]};
            f32x4 d2 = {b2r[2][0], b2r[2][1], b2r[2][2], b2r[2][3]};
            f32x4 d3 = {b2r[3][0], b2r[3][1], b2r[3][2], b2r[3][3]};
            d0 = __builtin_amdgcn_mfma_f32_16x16x32_bf16(w2r[0], B0, d0, 0, 0, 0);
            d1 = __builtin_amdgcn_mfma_f32_16x16x32_bf16(w2r[3], B0, d1, 0, 0, 0);
            d2 = __builtin_amdgcn_mfma_f32_16x16x32_bf16(w2r[6], B0, d2, 0, 0, 0);
            d3 = __builtin_amdgcn_mfma_f32_16x16x32_bf16(w2r[9], B0, d3, 0, 0, 0);
            d0 = __builtin_amdgcn_mfma_f32_16x16x32_bf16(w2r[1], B1, d0, 0, 0, 0);
            d1 = __builtin_amdgcn_mfma_f32_16x16x32_bf16(w2r[4], B1, d1, 0, 0, 0);
            d2 = __builtin_amdgcn_mfma_f32_16x16x32_bf16(w2r[7], B1, d2, 0, 0, 0);
            d3 = __builtin_amdgcn_mfma_f32_16x16x32_bf16(w2r[10], B1, d3, 0, 0, 0);
            d0 = __builtin_amdgcn_mfma_f32_16x16x32_bf16(w2r[2], C2, d0, 0, 0, 0);
            d1 = __builtin_amdgcn_mfma_f32_16x16x32_bf16(w2r[5], C2, d1, 0, 0, 0);
            d2 = __builtin_amdgcn_mfma_f32_16x16x32_bf16(w2r[8], C2, d2, 0, 0, 0);
            d3 = __builtin_amdgcn_mfma_f32_16x16x32_bf16(w2r[11], C2, d3, 0, 0, 0);
            float h2v[4];
#pragma unroll
            for (int e = 0; e < 4; e++) {
                c2[e] = sigf(d1[e]) * c2[e] + sigf(d0[e]) * tanh_f(d2[e]);
                h2v[e] = sigf(d3[e]) * tanh_f(c2[e]);
            }
            uint2 pk = make_uint2(cvtpk_bf16(h2v[0], h2v[1]), cvtpk_bf16(h2v[2], h2v[3]));
            *(uint2*)(H2_raw[p] + (((unsigned)(l15 * 64 + u0 * 2)) ^ jx4)) = pk;
            if (s == 15) *(float4*)(&L2F[l15][u0]) = make_float4(h2v[0], h2v[1], h2v[2], h2v[3]);
        }
        if (s < 15) phase1(H1_raw[p ^ 1], BEn, B0, B1, (s + 1) == 15);
    }

    __syncthreads();
    // ---- epilogue: residual + QKV projection ----
    {
        const int j = tid >> 4, rb = tid & 15;
        const int gb = base + j;
        const float4* l1p = (const float4*)(&L1F[j][0]);
        const float4* l2p = (const float4*)(&L2F[j][0]);
#pragma unroll
        for (int rep = 0; rep < 6; rep++) {
            int row = rb + 16 * rep;   // 0..95
            float acc = attn_b[row];
            const float4* wrow = (const float4*)(attn_w + row * 32);
#pragma unroll
            for (int k4 = 0; k4 < 8; k4++) {
                float4 lv1 = l1p[k4];
                float4 lv2 = l2p[k4];
                float4 ww = wrow[k4];
                float lx = lv2.x + lv1.x, ly = lv2.y + lv1.y, lz = lv2.z + lv1.z, lw = lv2.w + lv1.w;
                acc += lx * ww.x + ly * ww.y + lz * ww.z + lw * ww.w;
            }
            if (row < 32) Q[gb * 32 + row] = acc * 0.35355339059327373f;  // 1/sqrt(8)
            else if (row < 64) K[gb * 32 + (row - 32)] = acc;
            else V[gb * 32 + (row - 64)] = acc;
        }
    }
#undef LDBE
#undef LDB0
#undef LDB1
#undef LDC2
}

// ---------------- attention over batch dim. 16 chunks x 16 l-tiles = 256 blocks.
__global__ __launch_bounds__(256, 2) void attn_kernel(
    const float* __restrict__ Q, const float* __restrict__ K, const float* __restrict__ V,
    float* __restrict__ pm, float* __restrict__ ps, float* __restrict__ pacc) {
    int c = blockIdx.x & 15, lt = blockIdx.x >> 4;
    int t = threadIdx.x;
    int h = t >> 6, l = lt * 64 + (t & 63);
    __shared__ __align__(16) float Ks[64 * 32];
    __shared__ __align__(16) float Vs[64 * 32];
    {
        const float4* Kg = (const float4*)(K + c * 2048);
        const float4* Vg = (const float4*)(V + c * 2048);
        float4* K4 = (float4*)Ks;
        float4* V4 = (float4*)Vs;
        K4[t] = Kg[t];
        K4[t + 256] = Kg[t + 256];
        V4[t] = Vg[t];
        V4[t + 256] = Vg[t + 256];
    }
    const float4* qg = (const float4*)(Q + l * 32 + h * 8);
    float4 q0 = qg[0], q1 = qg[1];
    __syncthreads();
    float m_r = -1e30f, l_r = 0.f;
    float4 acc0 = {0, 0, 0, 0}, acc1 = {0, 0, 0, 0};
#pragma unroll 4
    for (int m = 0; m < 64; m++) {
        const float4* k4 = (const float4*)(Ks + m * 32 + h * 8);
        float4 ka = k4[0], kb = k4[1];
        float s = q0.x * ka.x + q0.y * ka.y + q0.z * ka.z + q0.w * ka.w +
                  q1.x * kb.x + q1.y * kb.y + q1.z * kb.z + q1.w * kb.w;
        const float4* v4 = (const float4*)(Vs + m * 32 + h * 8);
        float4 va = v4[0], vb = v4[1];
        float nm = fmaxf(m_r, s);
        float f = __expf(m_r - nm);
        float pp = __expf(s - nm);
        l_r = l_r * f + pp;
        acc0.x = acc0.x * f + pp * va.x;
        acc0.y = acc0.y * f + pp * va.y;
        acc0.z = acc0.z * f + pp * va.z;
        acc0.w = acc0.w * f + pp * va.w;
        acc1.x = acc1.x * f + pp * vb.x;
        acc1.y = acc1.y * f + pp * vb.y;
        acc1.z = acc1.z * f + pp * vb.z;
        acc1.w = acc1.w * f + pp * vb.w;
        m_r = nm;
    }
    int idx = (c * 4 + h) * 1024 + l;
    pm[idx] = m_r;
    ps[idx] = l_r;
    float4* po = (float4*)(pacc + idx * 8);
    po[0] = acc0;
    po[1] = acc1;
}

// ---------------- combine 16 chunks + out-proj + MLP head + sigmoid. One wave per l.
__global__ __launch_bounds__(256) void head_kernel(
    const float* __restrict__ pm, const float* __restrict__ ps, const float* __restrict__ pacc,
    const float* __restrict__ ow, const float* __restrict__ ob,
    const float* __restrict__ d1w, const float* __restrict__ d1b,
    const float* __restrict__ g1, const float* __restrict__ b1,
    const float* __restrict__ d2w, const float* __restrict__ d2b,
    const float* __restrict__ g2, const float* __restrict__ b2,
    const float* __restrict__ d3w, const float* __restrict__ d3b,
    float* __restrict__ out) {
    int wid = threadIdx.x >> 6, j = threadIdx.x & 63;
    int l = blockIdx.x * 4 + wid;
    __shared__ float att_s[4][32], z_s[4][32], r1s[4][64];
    if (j < 32) {
        int h = j >> 3, d = j & 7;
        float M = -1e30f;
#pragma unroll
        for (int c = 0; c < 16; c++) M = fmaxf(M, pm[(c * 4 + h) * 1024 + l]);
        float den = 0.f, num = 0.f;
#pragma unroll
        for (int c = 0; c < 16; c++) {
            int idx = (c * 4 + h) * 1024 + l;
            float e = __expf(pm[idx] - M);
            den += e * ps[idx];
            num += e * pacc[idx * 8 + d];
        }
        att_s[wid][j] = num / den;
    }
    __syncthreads();
    if (j < 32) {
        float a = ob[j];
        const float4* aw = (const float4*)(&att_s[wid][0]);
        const float4* wr = (const float4*)(ow + j * 32);
#pragma unroll
        for (int k4 = 0; k4 < 8; k4++) {
            float4 u = aw[k4], wv = wr[k4];
            a += u.x * wv.x + u.y * wv.y + u.z * wv.z + u.w * wv.w;
        }
        z_s[wid][j] = a;
    }
    __syncthreads();
    const float inv = rsqrtf(1.0f + 1e-5f);
    {
        float a = d1b[j];
        const float4* zw = (const float4*)(&z_s[wid][0]);
        const float4* wr = (const float4*)(d1w + j * 32);
#pragma unroll
        for (int k4 = 0; k4 < 8; k4++) {
            float4 u = zw[k4], wv = wr[k4];
            a += u.x * wv.x + u.y * wv.y + u.z * wv.z + u.w * wv.w;
        }
        a = a * (g1[j] * inv) + b1[j];
        r1s[wid][j] = fmaxf(a, 0.f);
    }
    __syncthreads();
    if (j < 32) {
        float a = d2b[j];
        const float4* rw = (const float4*)(&r1s[wid][0]);
        const float4* wr = (const float4*)(d2w + j * 64);
#pragma unroll
        for (int k4 = 0; k4 < 16; k4++) {
            float4 u = rw[k4], wv = wr[k4];
            a += u.x * wv.x + u.y * wv.y + u.z * wv.z + u.w * wv.w;
        }
        a = a * (g2[j] * inv) + b2[j];
        float r2 = fmaxf(a, 0.f);
        float p = r2 * d3w[j];
        p += __shfl_down(p, 16);
        p += __shfl_down(p, 8);
        p += __shfl_down(p, 4);
        p += __shfl_down(p, 2);
        p += __shfl_down(p, 1);
        if (j == 0) out[l] = __builtin_amdgcn_rcpf(1.0f + __expf(-(p + d3b[0])));
    }
}

extern "C" void kernel_launch(void* const* d_in, const int* in_sizes, int n_in,
                              void* d_out, int out_size, void* d_ws, size_t ws_size,
                              hipStream_t stream) {
    const float* x      = (const float*)d_in[0];
    const float* emb_w  = (const float*)d_in[1];
    const float* emb_b  = (const float*)d_in[2];
    const float* l1_wih = (const float*)d_in[3];
    const float* l1_whh = (const float*)d_in[4];
    const float* l1_bih = (const float*)d_in[5];
    const float* l1_bhh = (const float*)d_in[6];
    const float* l2_wih = (const float*)d_in[7];
    const float* l2_whh = (const float*)d_in[8];
    const float* l2_bih = (const float*)d_in[9];
    const float* l2_bhh = (const float*)d_in[10];
    const float* attn_w = (const float*)d_in[11];
    const float* attn_b = (const float*)d_in[12];
    const float* attn_ow = (const float*)d_in[13];
    const float* attn_ob = (const float*)d_in[14];
    const float* d1_w  = (const float*)d_in[15];
    const float* d1_b  = (const float*)d_in[16];
    const float* bn1_g = (const float*)d_in[17];
    const float* bn1_b = (const float*)d_in[18];
    const float* d2_w  = (const float*)d_in[19];
    const float* d2_b  = (const float*)d_in[20];
    const float* bn2_g = (const float*)d_in[21];
    const float* bn2_b = (const float*)d_in[22];
    const float* d3_w  = (const float*)d_in[23];
    const float* d3_b  = (const float*)d_in[24];
    float* out = (float*)d_out;

    float* ws   = (float*)d_ws;
    float* Q    = ws;               // 32768
    float* K    = ws + 32768;       // 32768
    float* V    = ws + 65536;       // 32768
    float* pm   = ws + 98304;       // 65536
    float* ps   = ws + 163840;      // 65536
    float* pacc = ws + 229376;      // 524288   (end: 753664 floats ~2.95 MB)

    lstm_kernel<<<64, 256, 0, stream>>>(x, emb_w, emb_b, l1_wih, l1_whh, l1_bih, l1_bhh,
                                        l2_wih, l2_whh, l2_bih, l2_bhh,
                                        attn_w, attn_b, Q, K, V);
    attn_kernel<<<256, 256, 0, stream>>>(Q, K, V, pm, ps, pacc);
    head_kernel<<<256, 256, 0, stream>>>(pm, ps, pacc, attn_ow, attn_ob, d1_w, d1_b,
                                         bn1_g, bn1_b, d2_w, d2_b, bn2_g, bn2_b,
                                         d3_w, d3_b, out);
}

// Round 11
// 140.989 us; speedup vs baseline: 1.2480x; 1.0097x over previous
//
#include <hip/hip_runtime.h>
#include <math.h>

// Model dims: B=1024, S=16, E=32, NH=4, H=64 (lstm1), 32 (lstm2)
// lstm_kernel: 64 blocks x 256 threads, 16 batch elems/block, MFMA bf16 gates.
// R11: opaque-asm forced register residency for LSTM2 weight frags;
//      fully straight-line loop body (no divergent compute) so the scheduler
//      can interleave phase1 MFMAs with phase2 activation latency.

typedef __attribute__((ext_vector_type(8))) short short8v;   // 8 bf16 = 4 VGPR
typedef __attribute__((ext_vector_type(4))) float f32x4;

__device__ __forceinline__ float sigf(float x) {
    float e = __expf(-x);
    return __builtin_amdgcn_rcpf(1.0f + e);
}
__device__ __forceinline__ float tanh_f(float x) {
    float a = fabsf(x);
    float e = __expf(2.0f * a);
    float t = 1.0f - 2.0f * __builtin_amdgcn_rcpf(e + 1.0f);
    return copysignf(t, x);
}
__device__ __forceinline__ unsigned short f2bf(float f) {   // RTN f32->bf16 (preamble only)
    unsigned int u = __float_as_uint(f);
    unsigned int r = (u + 0x7FFFu + ((u >> 16) & 1u)) >> 16;
    return (unsigned short)r;
}
__device__ __forceinline__ unsigned cvtpk_bf16(float lo, float hi) {  // D.lo=bf16(lo), D.hi=bf16(hi)
    unsigned r;
    asm("v_cvt_pk_bf16_f32 %0, %1, %2" : "=v"(r) : "v"(lo), "v"(hi));
    return r;
}

// ---------------- fused embed+posenc+LSTM1+LSTM2+residual+QKV via MFMA ----------------
__global__ __launch_bounds__(256, 1) void lstm_kernel(
    const float* __restrict__ x,
    const float* __restrict__ emb_w, const float* __restrict__ emb_b,
    const float* __restrict__ wih1, const float* __restrict__ whh1,
    const float* __restrict__ bih1, const float* __restrict__ bhh1,
    const float* __restrict__ wih2, const float* __restrict__ whh2,
    const float* __restrict__ bih2, const float* __restrict__ bhh2,
    const float* __restrict__ attn_w, const float* __restrict__ attn_b,
    float* __restrict__ Q, float* __restrict__ K, float* __restrict__ V) {
    const int tid = threadIdx.x;
    const int w = tid >> 6, lane = tid & 63;
    const int l15 = lane & 15, q4 = lane >> 4;
    const int base = blockIdx.x * 16;

    __shared__ __align__(16) unsigned char E_raw[16 * 1024];   // E[16s][16j][32 bf16] swz
    __shared__ __align__(16) unsigned char H1_raw[2][2048];    // h1[buf][16j][64 bf16] swz
    __shared__ __align__(16) unsigned char H2_raw[2][1024];    // h2[buf][16j][32 bf16] swz
    __shared__ __align__(16) unsigned char WF2[24 * 1024];     // LSTM2 A-frags (staging only)
    __shared__ __align__(16) float L1F[16][64];
    __shared__ __align__(16) float L2F[16][32];

    const unsigned jx7 = (unsigned)(l15 & 7) << 4;   // H1 row = 128B: XOR bits 4-6
    const unsigned jx4 = (unsigned)(l15 & 3) << 4;   // H2/E row = 64B: XOR bits 4-5

    // ---- LSTM1 weight A-fragments in registers ----
    short8v w1f[4][3];   // tiles T = w + 4t (t = gate kind), slabs over [W1hh(64)|W1ih(32)]
#pragma unroll
    for (int t = 0; t < 4; t++) {
        const int row = (w + 4 * t) * 16 + l15;
#pragma unroll
        for (int sl = 0; sl < 3; sl++) {
            short8v f;
#pragma unroll
            for (int e = 0; e < 8; e++) {
                int k = sl * 32 + q4 * 8 + e;
                float v = (k < 64) ? whh1[row * 64 + k] : wih1[row * 32 + (k - 64)];
                f[e] = (short)f2bf(v);
            }
            w1f[t][sl] = f;
        }
    }

    // ---- stage LSTM2 A-fragments to LDS (hoisted to regs after the barrier) ----
    for (int f = w; f < 24; f += 4) {
        int t2 = f / 3, sl = f - t2 * 3;
        int row = t2 * 16 + l15;
        int koff = sl * 32 + q4 * 8;
        const float* src = (sl < 2) ? (wih2 + row * 64 + koff) : (whh2 + row * 32 + (koff - 64));
        float4 va = *(const float4*)(src);
        float4 vb = *(const float4*)(src + 4);
        short8v pk;
        pk[0] = (short)f2bf(va.x); pk[1] = (short)f2bf(va.y);
        pk[2] = (short)f2bf(va.z); pk[3] = (short)f2bf(va.w);
        pk[4] = (short)f2bf(vb.x); pk[5] = (short)f2bf(vb.y);
        pk[6] = (short)f2bf(vb.z); pk[7] = (short)f2bf(vb.w);
        *(short8v*)(&WF2[f * 1024 + lane * 16]) = pk;
    }

    // ---- biases ----
    float b1r[4][4];
#pragma unroll
    for (int t = 0; t < 4; t++)
#pragma unroll
        for (int e = 0; e < 4; e++) {
            int r = (w + 4 * t) * 16 + q4 * 4 + e;
            b1r[t][e] = bih1[r] + bhh1[r];
        }
    float b2r[4][4];
#pragma unroll
    for (int t = 0; t < 4; t++)
#pragma unroll
        for (int e = 0; e < 4; e++) {
            int r = ((w & 1) + 2 * t) * 16 + q4 * 4 + e;   // waves 2,3 mirror 0,1
            b2r[t][e] = bih2[r] + bhh2[r];
        }

    // ---- init: zero h buffers [1] (read by step 0), build E ----
    *(unsigned long long*)(H1_raw[1] + tid * 8) = 0ULL;
    if (tid < 128) *(unsigned long long*)(H2_raw[1] + tid * 8) = 0ULL;
    {
        const int je = tid >> 4, se = tid & 15;
        float xv = x[(base + je) * 16 + se];
        float ev[32];
#pragma unroll
        for (int ii = 0; ii < 16; ii++) {
            float d = __expf(-0.28782313662425574f * (float)(2 * ii));  // 10000^(-2i/32)
            float ang = (float)se * d;
            ev[2 * ii] = xv * emb_w[2 * ii] + emb_b[2 * ii] + __sinf(ang);
            ev[2 * ii + 1] = xv * emb_w[2 * ii + 1] + emb_b[2 * ii + 1] + __cosf(ang);
        }
        unsigned jm = (unsigned)(je & 3) << 4;
#pragma unroll
        for (int b = 0; b < 4; b++) {
            short8v pk;
#pragma unroll
            for (int e = 0; e < 8; e++) pk[e] = (short)f2bf(ev[b * 8 + e]);
            *(short8v*)(&E_raw[se * 1024 + je * 64 + (((unsigned)(b * 16)) ^ jm)]) = pk;
        }
    }
    float c1[4] = {0.f, 0.f, 0.f, 0.f};
    float c2[4] = {0.f, 0.f, 0.f, 0.f};

    const int u0 = w * 16 + q4 * 4;

#define LDBE(S)  (*(const short8v*)(&E_raw[(S) * 1024] + (((unsigned)(l15 * 64 + q4 * 16)) ^ jx4)))
#define LDB0(HP) (*(const short8v*)((HP) + (((unsigned)(l15 * 128 + q4 * 16)) ^ jx7)))
#define LDB1(HP) (*(const short8v*)((HP) + (((unsigned)(l15 * 128 + 64 + q4 * 16)) ^ jx7)))
#define LDC2(HP) (*(const short8v*)((HP) + (((unsigned)(l15 * 64 + q4 * 16)) ^ jx4)))

    __syncthreads();   // init + WF2 staging visible

    // ---- hoist LSTM2 weight frags to registers; opaque asm defeats re-load CSE ----
    f32x4 w2rf[12];   // [t*3+sl], tiles T2 = (w&1) + 2t
#pragma unroll
    for (int t = 0; t < 4; t++)
#pragma unroll
        for (int sl = 0; sl < 3; sl++)
            w2rf[t * 3 + sl] =
                *(const f32x4*)(&WF2[((((w & 1) + 2 * t) * 3 + sl) << 10) + lane * 16]);
#pragma unroll
    for (int i = 0; i < 12; i++) asm volatile("" : "+v"(w2rf[i]));
#define W2R(I) (__builtin_bit_cast(short8v, w2rf[I]))

    // --- phase1 MFMA block: gates1 pre-acts for [E-slab, h1-slab0, h1-slab1] ---
    auto p1_mfma = [&](short8v BE, short8v B0, short8v B1,
                       f32x4& a0, f32x4& a1, f32x4& a2, f32x4& a3) {
        a0 = {b1r[0][0], b1r[0][1], b1r[0][2], b1r[0][3]};
        a1 = {b1r[1][0], b1r[1][1], b1r[1][2], b1r[1][3]};
        a2 = {b1r[2][0], b1r[2][1], b1r[2][2], b1r[2][3]};
        a3 = {b1r[3][0], b1r[3][1], b1r[3][2], b1r[3][3]};
        a0 = __builtin_amdgcn_mfma_f32_16x16x32_bf16(w1f[0][2], BE, a0, 0, 0, 0);
        a1 = __builtin_amdgcn_mfma_f32_16x16x32_bf16(w1f[1][2], BE, a1, 0, 0, 0);
        a2 = __builtin_amdgcn_mfma_f32_16x16x32_bf16(w1f[2][2], BE, a2, 0, 0, 0);
        a3 = __builtin_amdgcn_mfma_f32_16x16x32_bf16(w1f[3][2], BE, a3, 0, 0, 0);
        a0 = __builtin_amdgcn_mfma_f32_16x16x32_bf16(w1f[0][0], B0, a0, 0, 0, 0);
        a1 = __builtin_amdgcn_mfma_f32_16x16x32_bf16(w1f[1][0], B0, a1, 0, 0, 0);
        a2 = __builtin_amdgcn_mfma_f32_16x16x32_bf16(w1f[2][0], B0, a2, 0, 0, 0);
        a3 = __builtin_amdgcn_mfma_f32_16x16x32_bf16(w1f[3][0], B0, a3, 0, 0, 0);
        a0 = __builtin_amdgcn_mfma_f32_16x16x32_bf16(w1f[0][1], B1, a0, 0, 0, 0);
        a1 = __builtin_amdgcn_mfma_f32_16x16x32_bf16(w1f[1][1], B1, a1, 0, 0, 0);
        a2 = __builtin_amdgcn_mfma_f32_16x16x32_bf16(w1f[2][1], B1, a2, 0, 0, 0);
        a3 = __builtin_amdgcn_mfma_f32_16x16x32_bf16(w1f[3][1], B1, a3, 0, 0, 0);
    };
    // --- phase1 activation + h1 write ---
    auto p1_act = [&](f32x4 a0, f32x4 a1, f32x4 a2, f32x4 a3,
                      unsigned char* H1n, bool wrL1F) {
        float h1v[4];
#pragma unroll
        for (int e = 0; e < 4; e++) {
            c1[e] = sigf(a1[e]) * c1[e] + sigf(a0[e]) * tanh_f(a2[e]);
            h1v[e] = sigf(a3[e]) * tanh_f(c1[e]);
        }
        uint2 pk = make_uint2(cvtpk_bf16(h1v[0], h1v[1]), cvtpk_bf16(h1v[2], h1v[3]));
        *(uint2*)(H1n + (((unsigned)(l15 * 128 + u0 * 2)) ^ jx7)) = pk;
        if (wrL1F) *(float4*)(&L1F[l15][u0]) = make_float4(h1v[0], h1v[1], h1v[2], h1v[3]);
    };

    // pre-loop: phase1(0) from zeros, writes H1_raw[0]
    {
        f32x4 a0, a1, a2, a3;
        p1_mfma(LDBE(0), LDB0(H1_raw[1]), LDB1(H1_raw[1]), a0, a1, a2, a3);
        p1_act(a0, a1, a2, a3, H1_raw[0], false);
    }

#pragma unroll 2
    for (int s = 0; s < 16; s++) {
        const int p = s & 1;
        __syncthreads();   // h1(s), h2(s-1) visible
        // ---- batched LDS reads ----
        short8v B0 = LDB0(H1_raw[p]);
        short8v B1 = LDB1(H1_raw[p]);
        short8v BEn = LDBE((s < 15) ? (s + 1) : 15);
        short8v C2 = LDC2(H2_raw[p ^ 1]);
        // ---- phase2 MFMAs (ALL waves; waves 2,3 compute identical values) ----
        f32x4 d0 = {b2r[0][0], b2r[0][1], b2r[0][2], b2r[0][3]};
        f32x4 d1 = {b2r[1][0], b2r[1][1], b2r[1][2], b2r[1][3]};
        f32x4 d2 = {b2r[2][0], b2r[2][1], b2r[2][2], b2r[2][3]};
        f32x4 d3 = {b2r[3][0], b2r[3][1], b2r[3][2], b2r[3][3]};
        d0 = __builtin_amdgcn_mfma_f32_16x16x32_bf16(W2R(0), B0, d0, 0, 0, 0);
        d1 = __builtin_amdgcn_mfma_f32_16x16x32_bf16(W2R(3), B0, d1, 0, 0, 0);
        d2 = __builtin_amdgcn_mfma_f32_16x16x32_bf16(W2R(6), B0, d2, 0, 0, 0);
        d3 = __builtin_amdgcn_mfma_f32_16x16x32_bf16(W2R(9), B0, d3, 0, 0, 0);
        d0 = __builtin_amdgcn_mfma_f32_16x16x32_bf16(W2R(1), B1, d0, 0, 0, 0);
        d1 = __builtin_amdgcn_mfma_f32_16x16x32_bf16(W2R(4), B1, d1, 0, 0, 0);
        d2 = __builtin_amdgcn_mfma_f32_16x16x32_bf16(W2R(7), B1, d2, 0, 0, 0);
        d3 = __builtin_amdgcn_mfma_f32_16x16x32_bf16(W2R(10), B1, d3, 0, 0, 0);
        d0 = __builtin_amdgcn_mfma_f32_16x16x32_bf16(W2R(2), C2, d0, 0, 0, 0);
        d1 = __builtin_amdgcn_mfma_f32_16x16x32_bf16(W2R(5), C2, d1, 0, 0, 0);
        d2 = __builtin_amdgcn_mfma_f32_16x16x32_bf16(W2R(8), C2, d2, 0, 0, 0);
        d3 = __builtin_amdgcn_mfma_f32_16x16x32_bf16(W2R(11), C2, d3, 0, 0, 0);
        // ---- phase1(s+1) MFMAs (independent of phase2 — overlaps d-latency) ----
        f32x4 a0, a1, a2, a3;
        p1_mfma(BEn, B0, B1, a0, a1, a2, a3);
        // ---- phase2 activation; only waves 0,1 store (8B, tiny divergence) ----
        {
            float h2v[4];
#pragma unroll
            for (int e = 0; e < 4; e++) {
                c2[e] = sigf(d1[e]) * c2[e] + sigf(d0[e]) * tanh_f(d2[e]);
                h2v[e] = sigf(d3[e]) * tanh_f(c2[e]);
            }
            uint2 pk = make_uint2(cvtpk_bf16(h2v[0], h2v[1]), cvtpk_bf16(h2v[2], h2v[3]));
            if (w < 2) {
                *(uint2*)(H2_raw[p] + (((unsigned)(l15 * 64 + u0 * 2)) ^ jx4)) = pk;
                if (s == 15) *(float4*)(&L2F[l15][u0]) =
                    make_float4(h2v[0], h2v[1], h2v[2], h2v[3]);
            }
        }
        // ---- phase1 activation + h1(s+1) write (s=15 instance is dead garbage) ----
        p1_act(a0, a1, a2, a3, H1_raw[p ^ 1], s == 14);
    }

    __syncthreads();
    // ---- epilogue: residual + QKV projection ----
    {
        const int j = tid >> 4, rb = tid & 15;
        const int gb = base + j;
        const float4* l1p = (const float4*)(&L1F[j][0]);
        const float4* l2p = (const float4*)(&L2F[j][0]);
#pragma unroll
        for (int rep = 0; rep < 6; rep++) {
            int row = rb + 16 * rep;   // 0..95
            float acc = attn_b[row];
            const float4* wrow = (const float4*)(attn_w + row * 32);
#pragma unroll
            for (int k4 = 0; k4 < 8; k4++) {
                float4 lv1 = l1p[k4];
                float4 lv2 = l2p[k4];
                float4 ww = wrow[k4];
                float lx = lv2.x + lv1.x, ly = lv2.y + lv1.y, lz = lv2.z + lv1.z, lw = lv2.w + lv1.w;
                acc += lx * ww.x + ly * ww.y + lz * ww.z + lw * ww.w;
            }
            if (row < 32) Q[gb * 32 + row] = acc * 0.35355339059327373f;  // 1/sqrt(8)
            else if (row < 64) K[gb * 32 + (row - 32)] = acc;
            else V[gb * 32 + (row - 64)] = acc;
        }
    }
#undef LDBE
#undef LDB0
#undef LDB1
#undef LDC2
#undef W2R
}

// ---------------- attention over batch dim. 16 chunks x 16 l-tiles = 256 blocks.
__global__ __launch_bounds__(256, 2) void attn_kernel(
    const float* __restrict__ Q, const float* __restrict__ K, const float* __restrict__ V,
    float* __restrict__ pm, float* __restrict__ ps, float* __restrict__ pacc) {
    int c = blockIdx.x & 15, lt = blockIdx.x >> 4;
    int t = threadIdx.x;
    int h = t >> 6, l = lt * 64 + (t & 63);
    __shared__ __align__(16) float Ks[64 * 32];
    __shared__ __align__(16) float Vs[64 * 32];
    {
        const float4* Kg = (const float4*)(K + c * 2048);
        const float4* Vg = (const float4*)(V + c * 2048);
        float4* K4 = (float4*)Ks;
        float4* V4 = (float4*)Vs;
        K4[t] = Kg[t];
        K4[t + 256] = Kg[t + 256];
        V4[t] = Vg[t];
        V4[t + 256] = Vg[t + 256];
    }
    const float4* qg = (const float4*)(Q + l * 32 + h * 8);
    float4 q0 = qg[0], q1 = qg[1];
    __syncthreads();
    float m_r = -1e30f, l_r = 0.f;
    float4 acc0 = {0, 0, 0, 0}, acc1 = {0, 0, 0, 0};
#pragma unroll 4
    for (int m = 0; m < 64; m++) {
        const float4* k4 = (const float4*)(Ks + m * 32 + h * 8);
        float4 ka = k4[0], kb = k4[1];
        float s = q0.x * ka.x + q0.y * ka.y + q0.z * ka.z + q0.w * ka.w +
                  q1.x * kb.x + q1.y * kb.y + q1.z * kb.z + q1.w * kb.w;
        const float4* v4 = (const float4*)(Vs + m * 32 + h * 8);
        float4 va = v4[0], vb = v4[1];
        float nm = fmaxf(m_r, s);
        float f = __expf(m_r - nm);
        float pp = __expf(s - nm);
        l_r = l_r * f + pp;
        acc0.x = acc0.x * f + pp * va.x;
        acc0.y = acc0.y * f + pp * va.y;
        acc0.z = acc0.z * f + pp * va.z;
        acc0.w = acc0.w * f + pp * va.w;
        acc1.x = acc1.x * f + pp * vb.x;
        acc1.y = acc1.y * f + pp * vb.y;
        acc1.z = acc1.z * f + pp * vb.z;
        acc1.w = acc1.w * f + pp * vb.w;
        m_r = nm;
    }
    int idx = (c * 4 + h) * 1024 + l;
    pm[idx] = m_r;
    ps[idx] = l_r;
    float4* po = (float4*)(pacc + idx * 8);
    po[0] = acc0;
    po[1] = acc1;
}

// ---------------- combine 16 chunks + out-proj + MLP head + sigmoid. One wave per l.
__global__ __launch_bounds__(256) void head_kernel(
    const float* __restrict__ pm, const float* __restrict__ ps, const float* __restrict__ pacc,
    const float* __restrict__ ow, const float* __restrict__ ob,
    const float* __restrict__ d1w, const float* __restrict__ d1b,
    const float* __restrict__ g1, const float* __restrict__ b1,
    const float* __restrict__ d2w, const float* __restrict__ d2b,
    const float* __restrict__ g2, const float* __restrict__ b2,
    const float* __restrict__ d3w, const float* __restrict__ d3b,
    float* __restrict__ out) {
    int wid = threadIdx.x >> 6, j = threadIdx.x & 63;
    int l = blockIdx.x * 4 + wid;
    __shared__ float att_s[4][32], z_s[4][32], r1s[4][64];
    if (j < 32) {
        int h = j >> 3, d = j & 7;
        float M = -1e30f;
#pragma unroll
        for (int c = 0; c < 16; c++) M = fmaxf(M, pm[(c * 4 + h) * 1024 + l]);
        float den = 0.f, num = 0.f;
#pragma unroll
        for (int c = 0; c < 16; c++) {
            int idx = (c * 4 + h) * 1024 + l;
            float e = __expf(pm[idx] - M);
            den += e * ps[idx];
            num += e * pacc[idx * 8 + d];
        }
        att_s[wid][j] = num / den;
    }
    __syncthreads();
    if (j < 32) {
        float a = ob[j];
        const float4* aw = (const float4*)(&att_s[wid][0]);
        const float4* wr = (const float4*)(ow + j * 32);
#pragma unroll
        for (int k4 = 0; k4 < 8; k4++) {
            float4 u = aw[k4], wv = wr[k4];
            a += u.x * wv.x + u.y * wv.y + u.z * wv.z + u.w * wv.w;
        }
        z_s[wid][j] = a;
    }
    __syncthreads();
    const float inv = rsqrtf(1.0f + 1e-5f);
    {
        float a = d1b[j];
        const float4* zw = (const float4*)(&z_s[wid][0]);
        const float4* wr = (const float4*)(d1w + j * 32);
#pragma unroll
        for (int k4 = 0; k4 < 8; k4++) {
            float4 u = zw[k4], wv = wr[k4];
            a += u.x * wv.x + u.y * wv.y + u.z * wv.z + u.w * wv.w;
        }
        a = a * (g1[j] * inv) + b1[j];
        r1s[wid][j] = fmaxf(a, 0.f);
    }
    __syncthreads();
    if (j < 32) {
        float a = d2b[j];
        const float4* rw = (const float4*)(&r1s[wid][0]);
        const float4* wr = (const float4*)(d2w + j * 64);
#pragma unroll
        for (int k4 = 0; k4 < 16; k4++) {
            float4 u = rw[k4], wv = wr[k4];
            a += u.x * wv.x + u.y * wv.y + u.z * wv.z + u.w * wv.w;
        }
        a = a * (g2[j] * inv) + b2[j];
        float r2 = fmaxf(a, 0.f);
        float p = r2 * d3w[j];
        p += __shfl_down(p, 16);
        p += __shfl_down(p, 8);
        p += __shfl_down(p, 4);
        p += __shfl_down(p, 2);
        p += __shfl_down(p, 1);
        if (j == 0) out[l] = __builtin_amdgcn_rcpf(1.0f + __expf(-(p + d3b[0])));
    }
}

extern "C" void kernel_launch(void* const* d_in, const int* in_sizes, int n_in,
                              void* d_out, int out_size, void* d_ws, size_t ws_size,
                              hipStream_t stream) {
    const float* x      = (const float*)d_in[0];
    const float* emb_w  = (const float*)d_in[1];
    const float* emb_b  = (const float*)d_in[2];
    const float* l1_wih = (const float*)d_in[3];
    const float* l1_whh = (const float*)d_in[4];
    const float* l1_bih = (const float*)d_in[5];
    const float* l1_bhh = (const float*)d_in[6];
    const float* l2_wih = (const float*)d_in[7];
    const float* l2_whh = (const float*)d_in[8];
    const float* l2_bih = (const float*)d_in[9];
    const float* l2_bhh = (const float*)d_in[10];
    const float* attn_w = (const float*)d_in[11];
    const float* attn_b = (const float*)d_in[12];
    const float* attn_ow = (const float*)d_in[13];
    const float* attn_ob = (const float*)d_in[14];
    const float* d1_w  = (const float*)d_in[15];
    const float* d1_b  = (const float*)d_in[16];
    const float* bn1_g = (const float*)d_in[17];
    const float* bn1_b = (const float*)d_in[18];
    const float* d2_w  = (const float*)d_in[19];
    const float* d2_b  = (const float*)d_in[20];
    const float* bn2_g = (const float*)d_in[21];
    const float* bn2_b = (const float*)d_in[22];
    const float* d3_w  = (const float*)d_in[23];
    const float* d3_b  = (const float*)d_in[24];
    float* out = (float*)d_out;

    float* ws   = (float*)d_ws;
    float* Q    = ws;               // 32768
    float* K    = ws + 32768;       // 32768
    float* V    = ws + 65536;       // 32768
    float* pm   = ws + 98304;       // 65536
    float* ps   = ws + 163840;      // 65536
    float* pacc = ws + 229376;      // 524288   (end: 753664 floats ~2.95 MB)

    lstm_kernel<<<64, 256, 0, stream>>>(x, emb_w, emb_b, l1_wih, l1_whh, l1_bih, l1_bhh,
                                        l2_wih, l2_whh, l2_bih, l2_bhh,
                                        attn_w, attn_b, Q, K, V);
    attn_kernel<<<256, 256, 0, stream>>>(Q, K, V, pm, ps, pacc);
    head_kernel<<<256, 256, 0, stream>>>(pm, ps, pacc, attn_ow, attn_ob, d1_w, d1_b,
                                         bn1_g, bn1_b, d2_w, d2_b, bn2_g, bn2_b,
                                         d3_w, d3_b, out);
}